// Round 3
// baseline (457.124 us; speedup 1.0000x reference)
//
#include <hip/hip_runtime.h>

// LSTM B=2048, T=512, I=1, H=64, O=1 (PyTorch gate order i,f,g,o).
// Step GEMM G[4x256] = H[4x64] @ W^T via single-product FP16 MFMA
// (fp32 accumulate; fp16 quantization error ~2e-4/gate, contractive).
// bias + x*w_ih folded into the MFMA C-init (C rows = batches).
// WG = 256 thr (4 waves) per 4 batches; grid = 512 (2 WG/CU).
// Phase 1: wave = gate block (4 N-tiles), W frags in 32 VGPRs.
// Phase 2: wave = batch, lane = j. Two barriers/step.

typedef float    f32x4 __attribute__((ext_vector_type(4)));
typedef _Float16 f16x8 __attribute__((ext_vector_type(8)));

namespace {
constexpr int Bsz = 2048;
constexpr int Tsz = 512;
constexpr int Hsz = 64;
constexpr int NB  = 4;    // batches per workgroup
}

__device__ __forceinline__ float sigm(float x) {
    return 1.0f / (1.0f + __expf(-x));
}
__device__ __forceinline__ float tanh_fast(float x) {
    float a = fabsf(x);
    float e = __expf(-2.0f * a);          // in (0,1]
    float t = (1.0f - e) / (1.0f + e);
    return copysignf(t, x);
}

__global__ __launch_bounds__(256, 2)
void lstm_mfma16(const float* __restrict__ x,      // [B,T]
                 const float* __restrict__ w_ih,   // [256]
                 const float* __restrict__ w_hh,   // [256,64]
                 const float* __restrict__ b_ih,   // [256]
                 const float* __restrict__ b_hh,   // [256]
                 const float* __restrict__ w_lin,  // [64]
                 const float* __restrict__ b_lin,  // [1]
                 float* __restrict__ out)          // [B]
{
    __shared__ __align__(16) float x_lds[Tsz][NB];   // 8 KB, [t][b] (16B rows)
    __shared__ __align__(16) char  hA[16 * 128];     // 2 KB, fp16 A-frag, swizzled
    __shared__ __align__(16) float g_raw[256 * NB];  // 4 KB, [gate][b]

    const int tid = threadIdx.x;
    const int wv  = tid >> 6;
    const int ln  = tid & 63;
    const int b0  = blockIdx.x * NB;

    // ---- stage x transposed into LDS: x_lds[t][b] ----
    #pragma unroll
    for (int it = 0; it < 2; ++it) {
        int i  = tid + it * 256;          // 0..511
        int b  = i >> 7;                  // 128 float4 per batch row
        int t4 = i & 127;
        float4 v = reinterpret_cast<const float4*>(x + (size_t)(b0 + b) * Tsz)[t4];
        x_lds[t4 * 4 + 0][b] = v.x;
        x_lds[t4 * 4 + 1][b] = v.y;
        x_lds[t4 * 4 + 2][b] = v.z;
        x_lds[t4 * 4 + 3][b] = v.w;
    }

    const int col = ln & 15;
    const int grp = ln >> 4;

    // ---- W fragments (one-time): wave wv owns gates [wv*64, wv*64+64) ----
    // B-operand tile tn, k-chunk kc: lane holds W[gate=base+col][kc*32+grp*8+e]
    f16x8 Wf[4][2];
    #pragma unroll
    for (int tn = 0; tn < 4; ++tn) {
        const float* wrow = w_hh + (size_t)(wv * 64 + tn * 16 + col) * Hsz;
        #pragma unroll
        for (int kc = 0; kc < 2; ++kc) {
            f16x8 w;
            #pragma unroll
            for (int e = 0; e < 8; ++e)
                w[e] = (_Float16)wrow[kc * 32 + grp * 8 + e];
            Wf[tn][kc] = w;
        }
    }

    // per-lane gate constants for C-init (gate = wv*64 + tn*16 + col)
    float wih[4], bias[4];
    #pragma unroll
    for (int tn = 0; tn < 4; ++tn) {
        const int g = wv * 64 + tn * 16 + col;
        wih[tn]  = w_ih[g];
        bias[tn] = b_ih[g] + b_hh[g];
    }

    // ---- A-fragment read offsets: row = ln&15, k = kc*32 + grp*8 + e ----
    const int arow  = ln & 15;
    const int sw    = (arow & 7) << 4;
    const int aoff0 = arow * 128 + ((0 * 64 + grp * 16) ^ sw);
    const int aoff1 = arow * 128 + ((1 * 64 + grp * 16) ^ sw);

    // ---- phase-2 ownership: batch = wv, j = ln ----
    // h write: row = wv, k = ln (2B), same XOR swizzle
    const int hwoff = wv * 128 + ((ln * 2) ^ (wv << 4));
    *(_Float16*)(hA + hwoff) = (_Float16)0.0f;   // h0 = 0 (rows 0..3)

    const float wlin  = w_lin[ln];
    const float blin0 = b_lin[0];

    float c = 0.0f, h = 0.0f;

    __syncthreads();

    for (int t = 0; t < Tsz; ++t) {
        // ===== phase 1: G = H @ W^T, C-init = x*w_ih + bias =====
        const float4 xb = *(const float4*)&x_lds[t][0];   // broadcast, 16B
        f16x8 A0 = *(const f16x8*)(hA + aoff0);
        f16x8 A1 = *(const f16x8*)(hA + aoff1);

        f32x4 acc[4];
        #pragma unroll
        for (int tn = 0; tn < 4; ++tn) {
            acc[tn][0] = fmaf(xb.x, wih[tn], bias[tn]);
            acc[tn][1] = fmaf(xb.y, wih[tn], bias[tn]);
            acc[tn][2] = fmaf(xb.z, wih[tn], bias[tn]);
            acc[tn][3] = fmaf(xb.w, wih[tn], bias[tn]);
        }

        #pragma unroll
        for (int tn = 0; tn < 4; ++tn)
            acc[tn] = __builtin_amdgcn_mfma_f32_16x16x32_f16(A0, Wf[tn][0], acc[tn], 0, 0, 0);
        #pragma unroll
        for (int tn = 0; tn < 4; ++tn)
            acc[tn] = __builtin_amdgcn_mfma_f32_16x16x32_f16(A1, Wf[tn][1], acc[tn], 0, 0, 0);

        // C layout: col = ln&15 (gate in tile), row = (ln>>4)*4 + reg.
        // Lanes 0..15 hold batches 0..3 in regs 0..3 -> b128 store.
        if (ln < 16) {
            #pragma unroll
            for (int tn = 0; tn < 4; ++tn)
                *(f32x4*)&g_raw[(wv * 64 + tn * 16 + ln) * 4] = acc[tn];
        }
        __syncthreads();

        // ===== phase 2: activations + state update (b = wv, j = ln) =====
        const float gi = g_raw[(0 * 64 + ln) * 4 + wv];
        const float gf = g_raw[(1 * 64 + ln) * 4 + wv];
        const float gg = g_raw[(2 * 64 + ln) * 4 + wv];
        const float go = g_raw[(3 * 64 + ln) * 4 + wv];

        const float ig = sigm(gi);
        const float fg = sigm(gf);
        const float tg = tanh_fast(gg);
        const float og = sigm(go);

        c = fmaf(fg, c, ig * tg);
        h = og * tanh_fast(c);

        *(_Float16*)(hA + hwoff) = (_Float16)h;

        __syncthreads();
    }

    // ---- out[b0+wv] = sum_j h[wv][j]*w_lin[j] + b_lin ----
    float p = h * wlin;
    #pragma unroll
    for (int off = 1; off < 64; off <<= 1)
        p += __shfl_xor(p, off, 64);
    if (ln == 0)
        out[b0 + wv] = p + blin0;
}

extern "C" void kernel_launch(void* const* d_in, const int* in_sizes, int n_in,
                              void* d_out, int out_size, void* d_ws, size_t ws_size,
                              hipStream_t stream) {
    const float* x     = (const float*)d_in[0];
    const float* w_ih  = (const float*)d_in[1];
    const float* w_hh  = (const float*)d_in[2];
    const float* b_ih  = (const float*)d_in[3];
    const float* b_hh  = (const float*)d_in[4];
    const float* w_lin = (const float*)d_in[5];
    const float* b_lin = (const float*)d_in[6];
    float* out = (float*)d_out;

    dim3 grid(Bsz / NB);   // 512
    dim3 block(256);
    lstm_mfma16<<<grid, block, 0, stream>>>(x, w_ih, w_hh, b_ih, b_hh,
                                            w_lin, b_lin, out);
}

// Round 4
// 281.083 us; speedup vs baseline: 1.6263x; 1.6263x over previous
//
#include <hip/hip_runtime.h>

// LSTM B=2048, T=512, I=1, H=64, O=1 (PyTorch gate order i,f,g,o).
// Step GEMM G[4x256] = H[4x64] @ W^T via single-product FP16 MFMA
// (fp32 accumulate), bias + x*w_ih folded into MFMA C-init.
// WG = 256 thr (4 waves) per 4 batches; grid = 512 (2 WG/CU for latency hiding).
// Phase 1: wave = gate block (4 N-tiles), W frags in 32 VGPRs, A = h in LDS
//          (fp16, XOR-swizzled, conflict-free b128 reads).
// Phase 2: thread = (b = tid&3, j = tid>>2) -> g_raw reads are g_raw[tid+256g],
//          stride-1, conflict-free (round-3's 8-way strided reads fixed).
// All sigmoid/tanh via v_rcp + v_exp (no slow div sequences), saturating.

typedef float    f32x4 __attribute__((ext_vector_type(4)));
typedef _Float16 f16x8 __attribute__((ext_vector_type(8)));

namespace {
constexpr int Bsz = 2048;
constexpr int Tsz = 512;
constexpr int Hsz = 64;
constexpr int NB  = 4;    // batches per workgroup
}

__device__ __forceinline__ float rcp_f(float x) { return __builtin_amdgcn_rcpf(x); }
__device__ __forceinline__ float sigm(float x) {
    // saturates: x->+inf: rcp(1)=1; x->-inf: rcp(inf)=0
    return rcp_f(1.0f + __expf(-x));
}
__device__ __forceinline__ float tanh_rcp(float x) {
    // 2*sigm(2x)-1; saturates to +-1 correctly
    return fmaf(2.0f, rcp_f(1.0f + __expf(-2.0f * x)), -1.0f);
}

__global__ __launch_bounds__(256, 2)
void lstm_v4(const float* __restrict__ x,      // [B,T]
             const float* __restrict__ w_ih,   // [256]
             const float* __restrict__ w_hh,   // [256,64]
             const float* __restrict__ b_ih,   // [256]
             const float* __restrict__ b_hh,   // [256]
             const float* __restrict__ w_lin,  // [64]
             const float* __restrict__ b_lin,  // [1]
             float* __restrict__ out)          // [B]
{
    __shared__ __align__(16) float x_lds[Tsz][NB];   // 8 KB, [t][b] (16B rows)
    __shared__ __align__(16) char  hA[16 * 128];     // 2 KB, fp16 A-frag, swizzled
    __shared__ __align__(16) float g_raw[256 * NB];  // 4 KB, [gate][b]

    const int tid = threadIdx.x;
    const int wv  = tid >> 6;
    const int ln  = tid & 63;
    const int b0  = blockIdx.x * NB;

    // ---- stage x transposed into LDS: x_lds[t][b] (one-time) ----
    #pragma unroll
    for (int it = 0; it < 2; ++it) {
        int i  = tid + it * 256;          // 0..511
        int b  = i >> 7;                  // 128 float4 per batch row
        int t4 = i & 127;
        float4 v = reinterpret_cast<const float4*>(x + (size_t)(b0 + b) * Tsz)[t4];
        x_lds[t4 * 4 + 0][b] = v.x;
        x_lds[t4 * 4 + 1][b] = v.y;
        x_lds[t4 * 4 + 2][b] = v.z;
        x_lds[t4 * 4 + 3][b] = v.w;
    }

    const int col = ln & 15;
    const int grp = ln >> 4;

    // ---- W fragments (one-time): wave wv owns gates [wv*64, wv*64+64) ----
    // B-operand tile tn, k-chunk kc: lane holds W[gate=base+col][kc*32+grp*8+e]
    f16x8 Wf[4][2];
    #pragma unroll
    for (int tn = 0; tn < 4; ++tn) {
        const float* wrow = w_hh + (size_t)(wv * 64 + tn * 16 + col) * Hsz;
        #pragma unroll
        for (int kc = 0; kc < 2; ++kc) {
            f16x8 w;
            #pragma unroll
            for (int e = 0; e < 8; ++e)
                w[e] = (_Float16)wrow[kc * 32 + grp * 8 + e];
            Wf[tn][kc] = w;
        }
    }

    // per-lane gate constants for C-init (gate = wv*64 + tn*16 + col)
    float wih[4], bias[4];
    #pragma unroll
    for (int tn = 0; tn < 4; ++tn) {
        const int g = wv * 64 + tn * 16 + col;
        wih[tn]  = w_ih[g];
        bias[tn] = b_ih[g] + b_hh[g];
    }

    // ---- A-fragment read offsets: row = col, k = kc*32 + grp*8 + e ----
    const int sw    = (col & 7) << 4;
    const int aoff0 = col * 128 + ((0 * 64 + grp * 16) ^ sw);
    const int aoff1 = col * 128 + ((1 * 64 + grp * 16) ^ sw);

    // ---- phase-2 ownership: b = tid&3, j = tid>>2 ----
    const int pb = tid & 3;
    const int pj = tid >> 2;                  // 0..63
    const float wlin  = w_lin[pj];
    const float blin0 = b_lin[0];
    // h write: row = pb, k = pj (2B), same XOR swizzle as A reads
    const int hwoff = pb * 128 + ((2 * pj) ^ (pb << 4));

    // zero hA (rows 4..15 stay zero forever -> no garbage in MFMA)
    reinterpret_cast<float2*>(hA)[tid] = make_float2(0.0f, 0.0f);

    float c = 0.0f, h = 0.0f;

    __syncthreads();

    for (int t = 0; t < Tsz; ++t) {
        // ===== phase 1: G = H @ W^T, C-init = x*w_ih + bias =====
        const float4 xb = *(const float4*)&x_lds[t][0];   // broadcast, free
        f16x8 A0 = *(const f16x8*)(hA + aoff0);
        f16x8 A1 = *(const f16x8*)(hA + aoff1);

        f32x4 acc[4];
        #pragma unroll
        for (int tn = 0; tn < 4; ++tn) {
            acc[tn][0] = fmaf(xb.x, wih[tn], bias[tn]);
            acc[tn][1] = fmaf(xb.y, wih[tn], bias[tn]);
            acc[tn][2] = fmaf(xb.z, wih[tn], bias[tn]);
            acc[tn][3] = fmaf(xb.w, wih[tn], bias[tn]);
        }

        #pragma unroll
        for (int tn = 0; tn < 4; ++tn)
            acc[tn] = __builtin_amdgcn_mfma_f32_16x16x32_f16(A0, Wf[tn][0], acc[tn], 0, 0, 0);
        #pragma unroll
        for (int tn = 0; tn < 4; ++tn)
            acc[tn] = __builtin_amdgcn_mfma_f32_16x16x32_f16(A1, Wf[tn][1], acc[tn], 0, 0, 0);

        // C layout: col = ln&15 (gate in tile), row = (ln>>4)*4 + reg.
        // Lanes 0..15 hold batches 0..3 in regs 0..3 -> b128 store, 2 lanes/bank-quad.
        if (ln < 16) {
            #pragma unroll
            for (int tn = 0; tn < 4; ++tn)
                *(f32x4*)&g_raw[(wv * 64 + tn * 16 + ln) * 4] = acc[tn];
        }
        __syncthreads();

        // ===== phase 2: activations, thread = (pb, pj) =====
        // g_raw[(g*64+pj)*4 + pb] == g_raw[g*256 + tid]  -> stride-1, conflict-free
        const float gi = g_raw[tid +   0];
        const float gf = g_raw[tid + 256];
        const float gg = g_raw[tid + 512];
        const float go = g_raw[tid + 768];

        const float ig = sigm(gi);
        const float fg = sigm(gf);
        const float tg = tanh_rcp(gg);
        const float og = sigm(go);

        c = fmaf(fg, c, ig * tg);
        h = og * tanh_rcp(c);

        *(_Float16*)(hA + hwoff) = (_Float16)h;

        __syncthreads();
    }

    // ---- out[b] = sum_j h[b][j]*w_lin[j] + b_lin ----
    // lane = (jloc<<2)|b within wave: reduce over j bits (offsets 4..32)
    float p = h * wlin;
    #pragma unroll
    for (int off = 4; off < 64; off <<= 1)
        p += __shfl_xor(p, off, 64);
    if (ln < 4) g_raw[wv * 4 + ln] = p;    // per-wave partial for batch ln
    __syncthreads();
    if (tid < 4)
        out[b0 + tid] = g_raw[tid] + g_raw[4 + tid] +
                        g_raw[8 + tid] + g_raw[12 + tid] + blin0;
}

extern "C" void kernel_launch(void* const* d_in, const int* in_sizes, int n_in,
                              void* d_out, int out_size, void* d_ws, size_t ws_size,
                              hipStream_t stream) {
    const float* x     = (const float*)d_in[0];
    const float* w_ih  = (const float*)d_in[1];
    const float* w_hh  = (const float*)d_in[2];
    const float* b_ih  = (const float*)d_in[3];
    const float* b_hh  = (const float*)d_in[4];
    const float* w_lin = (const float*)d_in[5];
    const float* b_lin = (const float*)d_in[6];
    float* out = (float*)d_out;

    dim3 grid(Bsz / NB);   // 512
    dim3 block(256);
    lstm_v4<<<grid, block, 0, stream>>>(x, w_ih, w_hh, b_ih, b_hh,
                                        w_lin, b_lin, out);
}